// Round 2
// baseline (85054.889 us; speedup 1.0000x reference)
//
#include <hip/hip_runtime.h>

// ============================================================================
// Interactor (attention-gated LSTM), MI355X gfx950. FP32 I/O (per reference);
// bf16 internally for MFMA. Design: one-shot cvt of W_R/W_hh/W_ih to bf16 +
// 3 MFMA GEMMs (S_proj, V_proj, G) + persistent loop kernel (256 blocks x 512
// thr, 3 device-scope barriers/step). b_w dropped (softmax shift invariance).
// H_t_s folded into precomputed G. h carried bf16, c fp32, out fp32.
// ============================================================================

typedef unsigned short ushort_t;
typedef unsigned int uint_t;
typedef __attribute__((ext_vector_type(8))) short bf16x8;   // 8 x bf16 (4 VGPRs)
typedef __attribute__((ext_vector_type(4))) float f32x4;

#define MFMA_BF16 __builtin_amdgcn_mfma_f32_16x16x32_bf16

__device__ __forceinline__ float bf2f(ushort_t u) {
  return __builtin_bit_cast(float, (uint_t)u << 16);
}
__device__ __forceinline__ ushort_t f2bf(float f) {   // round-to-nearest-even
  uint_t u = __builtin_bit_cast(uint_t, f);
  u += 0x7FFFu + ((u >> 16) & 1u);
  return (ushort_t)(u >> 16);
}
__device__ __forceinline__ uint_t pk(float lo, float hi) {
  return (uint_t)f2bf(lo) | ((uint_t)f2bf(hi) << 16);
}
// 16 fp32 -> 16 bf16, two uint4 LDS stores (dst 16B-aligned)
__device__ __forceinline__ void stage16(ushort_t* dst, const float* src) {
  float4 a = *(const float4*)src,     b = *(const float4*)(src + 4);
  float4 c = *(const float4*)(src + 8), d = *(const float4*)(src + 12);
  uint4 lo = { pk(a.x,a.y), pk(a.z,a.w), pk(b.x,b.y), pk(b.z,b.w) };
  uint4 hi = { pk(c.x,c.y), pk(c.z,c.w), pk(d.x,d.y), pk(d.z,d.w) };
  *(uint4*)dst = lo; *(uint4*)(dst + 8) = hi;
}
// 8 fp32 -> one bf16 MFMA fragment (in-register)
__device__ __forceinline__ bf16x8 cvt8(const float* src) {
  float4 a = *(const float4*)src, b = *(const float4*)(src + 4);
  uint4 u = { pk(a.x,a.y), pk(a.z,a.w), pk(b.x,b.y), pk(b.z,b.w) };
  return __builtin_bit_cast(bf16x8, u);
}
__device__ __forceinline__ float tanh_(float x) {
  float e = __expf(2.f * x);                  // inf-safe: e=inf -> 1, e=0 -> -1
  return 1.f - 2.f * __builtin_amdgcn_rcpf(e + 1.f);
}
__device__ __forceinline__ float sigm_(float x) {
  return __builtin_amdgcn_rcpf(1.f + __expf(-x));
}

// fp32 -> bf16 elementwise (n multiple of 4)
__global__ __launch_bounds__(256) void cvt_kernel(
    const float* __restrict__ in, ushort_t* __restrict__ out, int n4) {
  int i = blockIdx.x * blockDim.x + threadIdx.x;
  if (i < n4) {
    float4 v = ((const float4*)in)[i];
    uint2 r = { pk(v.x, v.y), pk(v.z, v.w) };
    ((uint2*)out)[i] = r;
  }
}

// ---------------------------------------------------------------------------
// C = A * W^T (+bias), A:[M x K] fp32 row-major (lda), W:[N x K] fp32 row-major
// (ldw), out bf16 [M x ldo]. M,N multiples of 128, K of 32. fp32->bf16 cvt in
// staging. 128x128 tile, 4 waves (2x2), 64x64/wave, 16x16x32 MFMA.
// Fragment maps (learn_hip m89/m91): A lane: m=lane&15, k=quad*8+j;
// C/D lane: col=lane&15, row=quad*4+reg.
// ---------------------------------------------------------------------------
__global__ __launch_bounds__(256) void gemm_bt(
    const float* __restrict__ A, int lda,
    const float* __restrict__ W, int ldw,
    const float* __restrict__ bias1,
    ushort_t* __restrict__ out, int ldo, int K)
{
  __shared__ __align__(16) ushort_t sA[128][32];
  __shared__ __align__(16) ushort_t sW[128][32];
  const int tid = threadIdx.x;
  const int col0 = blockIdx.x * 128, row0 = blockIdx.y * 128;
  const int lane = tid & 63, wv = tid >> 6;
  const int wr = (wv & 1) * 64, wc = (wv >> 1) * 64;
  const int fr = lane & 15, quad = lane >> 4;
  const int sr = tid >> 1, skk = (tid & 1) * 16;   // staging role: row, k-half
  f32x4 acc[4][4] = {};
  for (int k0 = 0; k0 < K; k0 += 32) {
    stage16(&sA[sr][skk], &A[(size_t)(row0 + sr) * lda + k0 + skk]);
    stage16(&sW[sr][skk], &W[(size_t)(col0 + sr) * ldw + k0 + skk]);
    __syncthreads();
    bf16x8 af[4], wf[4];
    #pragma unroll
    for (int mt = 0; mt < 4; ++mt) af[mt] = *(const bf16x8*)&sA[wr + mt*16 + fr][quad*8];
    #pragma unroll
    for (int nt = 0; nt < 4; ++nt) wf[nt] = *(const bf16x8*)&sW[wc + nt*16 + fr][quad*8];
    #pragma unroll
    for (int mt = 0; mt < 4; ++mt)
      #pragma unroll
      for (int nt = 0; nt < 4; ++nt)
        acc[mt][nt] = MFMA_BF16(af[mt], wf[nt], acc[mt][nt], 0, 0, 0);
    __syncthreads();
  }
  #pragma unroll
  for (int nt = 0; nt < 4; ++nt) {
    int col = col0 + wc + nt*16 + fr;
    float bs = bias1 ? bias1[col] : 0.f;
    #pragma unroll
    for (int mt = 0; mt < 4; ++mt)
      #pragma unroll
      for (int r = 0; r < 4; ++r) {
        int row = row0 + wr + mt*16 + quad*4 + r;
        out[(size_t)row * ldo + col] = f2bf(acc[mt][nt][r] + bs);
      }
  }
}

// ---------------------------------------------------------------------------
// Device-scope barrier (counter+generation). Grid is exactly 256 blocks; one
// block/CU capacity >> needed, so all blocks co-resident with a plain launch.
// __threadfence() = agent-scope fence: emits L2 writeback (release) /
// invalidate (acquire) on gfx950 per the AMDGPU memory model.
// ---------------------------------------------------------------------------
__device__ __forceinline__ void grid_sync(unsigned* bar, unsigned* gen) {
  __syncthreads();
  if (threadIdx.x == 0) {
    __threadfence();  // release
    unsigned g = __hip_atomic_load(gen, __ATOMIC_RELAXED, __HIP_MEMORY_SCOPE_AGENT);
    unsigned old = __hip_atomic_fetch_add(bar, 1u, __ATOMIC_RELAXED, __HIP_MEMORY_SCOPE_AGENT);
    if (old == 255u) {
      __hip_atomic_store(bar, 0u, __ATOMIC_RELAXED, __HIP_MEMORY_SCOPE_AGENT);
      __threadfence();
      __hip_atomic_fetch_add(gen, 1u, __ATOMIC_RELAXED, __HIP_MEMORY_SCOPE_AGENT);
    } else {
      while (__hip_atomic_load(gen, __ATOMIC_RELAXED, __HIP_MEMORY_SCOPE_AGENT) == g)
        __builtin_amdgcn_s_sleep(2);
    }
    __threadfence();  // acquire
  }
  __syncthreads();
}

struct LoopArgs {
  const ushort_t *Sproj, *Vproj, *G;                // precomputed, bf16
  const ushort_t *WRb, *Whhb, *Wihb;                // bf16 weight copies
  const float *bR, *Ww, *bih, *bhh, *hv;            // raw fp32 inputs
  float *ru, *gpre, *beta;                          // per-step scratch, fp32
  ushort_t *hbf;                                    // recurrent h, bf16
  float *c;                                         // cell state, fp32
  unsigned *bar;                                    // [0]=counter, [16]=gen
  float *out;                                       // (B,T,HI) fp32
};

// 256 blocks x 512 threads, persistent over T=512 steps, 3 barriers/step.
__global__ __launch_bounds__(512, 2) void loop_kernel(LoopArgs p) {
  const int blk = blockIdx.x, tid = threadIdx.x;
  const int lane = tid & 63, wv = tid >> 6;
  const int fr = lane & 15, quad = lane >> 4;
  const int b4 = blk >> 2, q4 = blk & 3;           // P1/P2 role: (batch, quarter)

  __shared__ __align__(16) float s_ru[512];
  __shared__ __align__(16) float s_ww[512];
  __shared__ __align__(16) float s_beta[5120];
  __shared__ float s_alpha[80];
  __shared__ float s_gates[4][128];

  s_ww[tid] = p.Ww[tid];                           // W_w staged once (fp32)

  for (int t = 0; t < 512; ++t) {
    // ================= P0: r_u MFMA + gates-pre MFMA (reads hbf) ===========
    if (blk >= 192 && blk < 224) {
      // gates_pre[b][k] = h_prev.W_hh^T + hv_t.W_ih[:, :1024]^T + b_ih + b_hh
      // 256 waves: wave = (n-tile 0..127) x (m-half 0..1)
      int gw = (blk - 192) * 8 + wv;
      int n0 = (gw >> 1) * 16, mh2 = (gw & 1) * 2;
      int ncol = n0 + fr;
      f32x4 acc0 = {}, acc1 = {}, acc0b = {}, acc1b = {};
      #pragma unroll
      for (int kc = 0; kc < 16; ++kc) {            // K=512 over h (bf16)
        int ko = kc * 32 + quad * 8;
        bf16x8 wf = *(const bf16x8*)&p.Whhb[(size_t)ncol * 512 + ko];
        bf16x8 a0 = *(const bf16x8*)&p.hbf[(size_t)(mh2 * 16 + fr) * 512 + ko];
        bf16x8 a1 = *(const bf16x8*)&p.hbf[(size_t)((mh2 + 1) * 16 + fr) * 512 + ko];
        acc0 = MFMA_BF16(a0, wf, acc0, 0, 0, 0);
        acc1 = MFMA_BF16(a1, wf, acc1, 0, 0, 0);
      }
      #pragma unroll
      for (int kc = 0; kc < 32; ++kc) {            // K=1024 over hv_t (fp32->bf16)
        int ko = kc * 32 + quad * 8;
        bf16x8 wf = *(const bf16x8*)&p.Wihb[(size_t)ncol * 1536 + ko];
        bf16x8 a0 = cvt8(&p.hv[((size_t)(mh2 * 16 + fr) * 512 + t) * 1024 + ko]);
        bf16x8 a1 = cvt8(&p.hv[((size_t)((mh2 + 1) * 16 + fr) * 512 + t) * 1024 + ko]);
        acc0b = MFMA_BF16(a0, wf, acc0b, 0, 0, 0);
        acc1b = MFMA_BF16(a1, wf, acc1b, 0, 0, 0);
      }
      float bias = p.bih[ncol] + p.bhh[ncol];
      #pragma unroll
      for (int r = 0; r < 4; ++r) {                // C/D: row=quad*4+r, col=fr
        int row = mh2 * 16 + quad * 4 + r;
        p.gpre[(size_t)row * 2048 + ncol]        = acc0[r] + acc0b[r] + bias;
        p.gpre[(size_t)(row + 16) * 2048 + ncol] = acc1[r] + acc1b[r] + bias;
      }
    } else if (blk >= 16 && blk < 20) {
      // r_u[b][i] = h_prev.W_R^T + b_R + V_proj[b][t]; 32 waves
      int rw = (blk - 16) * 8 + wv;
      int ncol = rw * 16 + fr;
      f32x4 a4[4] = {};
      #pragma unroll
      for (int kc = 0; kc < 16; ++kc) {
        int ko = kc * 32 + quad * 8;
        bf16x8 wf = *(const bf16x8*)&p.WRb[(size_t)ncol * 512 + ko];
        #pragma unroll
        for (int mt = 0; mt < 4; ++mt) {
          bf16x8 af = *(const bf16x8*)&p.hbf[(size_t)(mt * 16 + fr) * 512 + ko];
          a4[mt] = MFMA_BF16(af, wf, a4[mt], 0, 0, 0);
        }
      }
      float br = p.bR[ncol];
      #pragma unroll
      for (int mt = 0; mt < 4; ++mt)
        #pragma unroll
        for (int r = 0; r < 4; ++r) {
          int b = mt * 16 + quad * 4 + r;
          p.ru[(size_t)b * 512 + ncol] =
              a4[mt][r] + br + bf2f(p.Vproj[((size_t)b * 512 + t) * 512 + ncol]);
        }
    }
    grid_sync(p.bar, p.bar + 16);

    // ================= P1: attention beta (all 256 blocks) =================
    s_ru[tid] = p.ru[(size_t)b4 * 512 + tid];
    __syncthreads();
    #pragma unroll
    for (int rr = 0; rr < 3; ++rr) {
      int nl = wv + 8 * rr;
      if (nl < 20) {
        int n = q4 * 20 + nl;
        const ushort_t* sp = &p.Sproj[((size_t)(b4 * 80 + n)) * 512 + lane * 8];
        uint4 sv = *(const uint4*)sp;
        float4 r0 = *(const float4*)&s_ru[lane * 8];
        float4 r1 = *(const float4*)&s_ru[lane * 8 + 4];
        float4 w0 = *(const float4*)&s_ww[lane * 8];
        float4 w1 = *(const float4*)&s_ww[lane * 8 + 4];
        float a = 0.f;
        a += tanh_(bf2f((ushort_t)(sv.x & 0xFFFF)) + r0.x) * w0.x;
        a += tanh_(bf2f((ushort_t)(sv.x >> 16))    + r0.y) * w0.y;
        a += tanh_(bf2f((ushort_t)(sv.y & 0xFFFF)) + r0.z) * w0.z;
        a += tanh_(bf2f((ushort_t)(sv.y >> 16))    + r0.w) * w0.w;
        a += tanh_(bf2f((ushort_t)(sv.z & 0xFFFF)) + r1.x) * w1.x;
        a += tanh_(bf2f((ushort_t)(sv.z >> 16))    + r1.y) * w1.y;
        a += tanh_(bf2f((ushort_t)(sv.w & 0xFFFF)) + r1.z) * w1.z;
        a += tanh_(bf2f((ushort_t)(sv.w >> 16))    + r1.w) * w1.w;
        #pragma unroll
        for (int off = 32; off > 0; off >>= 1) a += __shfl_xor(a, off, 64);
        if (lane == 0) p.beta[b4 * 80 + n] = a;    // b_w dropped (softmax-invariant)
      }
    }
    grid_sync(p.bar, p.bar + 16);

    // ================= P2: softmax(batch) + G-sum + LSTM ===================
    #pragma unroll
    for (int i = tid; i < 5120; i += 512) s_beta[i] = p.beta[i];
    __syncthreads();
    if (tid < 80) {                                // softmax over b, column n=tid
      float m = -1e30f;
      for (int b2 = 0; b2 < 64; ++b2) m = fmaxf(m, s_beta[b2 * 80 + tid]);
      float s = 0.f;
      for (int b2 = 0; b2 < 64; ++b2) s += __expf(s_beta[b2 * 80 + tid] - m);
      s_alpha[tid] = __expf(s_beta[b4 * 80 + tid] - m) * __builtin_amdgcn_rcpf(s);
    }
    __syncthreads();
    {
      int gg = tid >> 7, jj = tid & 127;
      int k = gg * 512 + q4 * 128 + jj;
      const ushort_t* Gp = &p.G[(size_t)b4 * 80 * 2048 + k];
      float v0 = 0, v1 = 0, v2 = 0, v3 = 0;
      for (int n = 0; n < 80; n += 4) {
        v0 += s_alpha[n]     * bf2f(Gp[(size_t)n * 2048]);
        v1 += s_alpha[n + 1] * bf2f(Gp[(size_t)(n + 1) * 2048]);
        v2 += s_alpha[n + 2] * bf2f(Gp[(size_t)(n + 2) * 2048]);
        v3 += s_alpha[n + 3] * bf2f(Gp[(size_t)(n + 3) * 2048]);
      }
      s_gates[gg][jj] = p.gpre[(size_t)b4 * 2048 + k] + ((v0 + v1) + (v2 + v3));
    }
    __syncthreads();
    if (tid < 128) {
      int j = q4 * 128 + tid;
      float ig = sigm_(s_gates[0][tid]);
      float fg = sigm_(s_gates[1][tid]);
      float g_ = tanh_(s_gates[2][tid]);
      float og = sigm_(s_gates[3][tid]);
      float cn = fg * p.c[b4 * 512 + j] + ig * g_;
      p.c[b4 * 512 + j] = cn;
      float hn = og * tanh_(cn);
      p.hbf[b4 * 512 + j] = f2bf(hn);
      p.out[((size_t)b4 * 512 + t) * 512 + j] = hn;
    }
    grid_sync(p.bar, p.bar + 16);
  }
}

// ===========================================================================
extern "C" void kernel_launch(void* const* d_in, const int* in_sizes, int n_in,
                              void* d_out, int out_size, void* d_ws, size_t ws_size,
                              hipStream_t stream) {
  (void)in_sizes; (void)n_in; (void)out_size; (void)ws_size;
  const float* hv   = (const float*)d_in[0];   // (64,512,1024)
  const float* hs   = (const float*)d_in[1];   // (64,80,512)
  const float* W_S  = (const float*)d_in[2];   // (512,512)
  const float* b_S  = (const float*)d_in[3];
  const float* W_V  = (const float*)d_in[4];   // (512,1024)
  const float* b_V  = (const float*)d_in[5];
  const float* W_R  = (const float*)d_in[6];   // (512,512)
  const float* b_R  = (const float*)d_in[7];
  const float* W_w  = (const float*)d_in[8];   // (1,512)
  /* d_in[9] = b_w: dropped (uniform shift under softmax over batch) */
  const float* W_ih = (const float*)d_in[10];  // (2048,1536)
  const float* b_ih = (const float*)d_in[11];
  const float* W_hh = (const float*)d_in[12];  // (2048,512)
  const float* b_hh = (const float*)d_in[13];

  char* ws = (char*)d_ws;
  unsigned long long off = 0;
  auto alloc = [&](unsigned long long bytes) {
    unsigned long long pp = off; off += (bytes + 255ull) & ~255ull; return pp;
  };
  ushort_t* Sproj = (ushort_t*)(ws + alloc(5120ull * 512 * 2));    // 5.25 MB
  ushort_t* Vproj = (ushort_t*)(ws + alloc(32768ull * 512 * 2));   // 33.6 MB
  ushort_t* G     = (ushort_t*)(ws + alloc(5120ull * 2048 * 2));   // 21 MB
  ushort_t* WRb   = (ushort_t*)(ws + alloc(512ull * 512 * 2));     // 0.5 MB
  ushort_t* Whhb  = (ushort_t*)(ws + alloc(2048ull * 512 * 2));    // 2.1 MB
  ushort_t* Wihb  = (ushort_t*)(ws + alloc(2048ull * 1536 * 2));   // 6.3 MB
  float*    ru    = (float*)(ws + alloc(64ull * 512 * 4));
  float*    gpre  = (float*)(ws + alloc(64ull * 2048 * 4));
  float*    beta  = (float*)(ws + alloc(64ull * 80 * 4));
  unsigned long long zoff = off;                                   // zero-init region
  ushort_t* hbf   = (ushort_t*)(ws + alloc(64ull * 512 * 2));
  float*    c     = (float*)(ws + alloc(64ull * 512 * 4));
  unsigned* bar   = (unsigned*)(ws + alloc(256));
  unsigned long long zsize = off - zoff;                           // total ~= 70 MB

  // bf16 weight copies for the in-loop MFMAs
  cvt_kernel<<<256,  256, 0, stream>>>(W_R,  WRb,  512 * 512 / 4);
  cvt_kernel<<<1024, 256, 0, stream>>>(W_hh, Whhb, 2048 * 512 / 4);
  cvt_kernel<<<3072, 256, 0, stream>>>(W_ih, Wihb, 2048 * 1536 / 4);

  // One-shot projections (fp32 in, bf16 MFMA, bf16 out):
  // S_proj = h_s . W_S^T + b_S          (M=5120,  N=512,  K=512)
  gemm_bt<<<dim3(4, 40), 256, 0, stream>>>(hs, 512, W_S, 512, b_S, Sproj, 512, 512);
  // V_proj = h_v . W_V^T + b_V          (M=32768, N=512,  K=1024)
  gemm_bt<<<dim3(4, 256), 256, 0, stream>>>(hv, 1024, W_V, 1024, b_V, Vproj, 512, 1024);
  // G = h_s . (W_ih[:,1024:])^T         (M=5120,  N=2048, K=512)
  gemm_bt<<<dim3(16, 40), 256, 0, stream>>>(hs, 512, W_ih + 1024, 1536, nullptr, G, 2048, 512);

  hipMemsetAsync(ws + zoff, 0, (size_t)zsize, stream);  // h=0, c=0, barrier=0

  LoopArgs la;
  la.Sproj = Sproj; la.Vproj = Vproj; la.G = G;
  la.WRb = WRb; la.Whhb = Whhb; la.Wihb = Wihb;
  la.bR = b_R; la.Ww = W_w; la.bih = b_ih; la.bhh = b_hh; la.hv = hv;
  la.ru = ru; la.gpre = gpre; la.beta = beta;
  la.hbf = hbf; la.c = c; la.bar = bar; la.out = (float*)d_out;
  loop_kernel<<<256, 512, 0, stream>>>(la);
}

// Round 3
// 24007.243 us; speedup vs baseline: 3.5429x; 3.5429x over previous
//
#include <hip/hip_runtime.h>

// ============================================================================
// Interactor (attention-gated LSTM), MI355X gfx950. FP32 I/O; bf16 MFMA inside.
// Round 3: FENCE-FREE persistent loop. All cross-block data moves via relaxed
// AGENT-scope atomics (sc0sc1 -> MALL coherence point, no L2 cache walks);
// barrier = syncthreads (drains vmcnt) + 2-level atomic tree + gen spin.
// X-projection (hv_t . W_ih[:, :1024]^T) hoisted to a one-shot GEMM when
// ws_size permits (134 MB); else computed in-loop (round-2 style fallback).
// b_w dropped (softmax shift-invariance). H_t_s folded into precomputed G.
// ============================================================================

typedef unsigned short ushort_t;
typedef unsigned int uint_t;
typedef __attribute__((ext_vector_type(8))) short bf16x8;   // 8 x bf16
typedef __attribute__((ext_vector_type(4))) float f32x4;

#define MFMA_BF16 __builtin_amdgcn_mfma_f32_16x16x32_bf16

__device__ __forceinline__ float bf2f(ushort_t u) {
  return __builtin_bit_cast(float, (uint_t)u << 16);
}
__device__ __forceinline__ ushort_t f2bf(float f) {   // round-to-nearest-even
  uint_t u = __builtin_bit_cast(uint_t, f);
  u += 0x7FFFu + ((u >> 16) & 1u);
  return (ushort_t)(u >> 16);
}
__device__ __forceinline__ uint_t pk(float lo, float hi) {
  return (uint_t)f2bf(lo) | ((uint_t)f2bf(hi) << 16);
}
__device__ __forceinline__ void stage16(ushort_t* dst, const float* src) {
  float4 a = *(const float4*)src,     b = *(const float4*)(src + 4);
  float4 c = *(const float4*)(src + 8), d = *(const float4*)(src + 12);
  uint4 lo = { pk(a.x,a.y), pk(a.z,a.w), pk(b.x,b.y), pk(b.z,b.w) };
  uint4 hi = { pk(c.x,c.y), pk(c.z,c.w), pk(d.x,d.y), pk(d.z,d.w) };
  *(uint4*)dst = lo; *(uint4*)(dst + 8) = hi;
}
__device__ __forceinline__ bf16x8 cvt8(const float* src) {
  float4 a = *(const float4*)src, b = *(const float4*)(src + 4);
  uint4 u = { pk(a.x,a.y), pk(a.z,a.w), pk(b.x,b.y), pk(b.z,b.w) };
  return __builtin_bit_cast(bf16x8, u);
}
__device__ __forceinline__ float tanh_(float x) {
  float e = __expf(2.f * x);
  return 1.f - 2.f * __builtin_amdgcn_rcpf(e + 1.f);
}
__device__ __forceinline__ float sigm_(float x) {
  return __builtin_amdgcn_rcpf(1.f + __expf(-x));
}

// -------- device-coherent (MALL) accessors: no fences, no cache walks -------
__device__ __forceinline__ float ldcg_f(const float* p) {
  return __hip_atomic_load(p, __ATOMIC_RELAXED, __HIP_MEMORY_SCOPE_AGENT);
}
__device__ __forceinline__ void stcg_f(float* p, float v) {
  __hip_atomic_store(p, v, __ATOMIC_RELAXED, __HIP_MEMORY_SCOPE_AGENT);
}
__device__ __forceinline__ uint_t ldcg_u(const uint_t* p) {
  return __hip_atomic_load(p, __ATOMIC_RELAXED, __HIP_MEMORY_SCOPE_AGENT);
}
__device__ __forceinline__ void stcg_u(uint_t* p, uint_t v) {
  __hip_atomic_store(p, v, __ATOMIC_RELAXED, __HIP_MEMORY_SCOPE_AGENT);
}

// fp32 -> bf16 elementwise (n4 = count of float4 groups)
__global__ __launch_bounds__(256) void cvt_kernel(
    const float* __restrict__ in, ushort_t* __restrict__ out, int n4) {
  int i = blockIdx.x * blockDim.x + threadIdx.x;
  if (i < n4) {
    float4 v = ((const float4*)in)[i];
    uint2 r = { pk(v.x, v.y), pk(v.z, v.w) };
    ((uint2*)out)[i] = r;
  }
}

// W_ih[:, :1024] fp32 -> bf16 [2048][1024] (fallback path only)
__global__ __launch_bounds__(256) void cvt_wih_kernel(
    const float* __restrict__ in, ushort_t* __restrict__ out) {
  int i = blockIdx.x * blockDim.x + threadIdx.x;   // [0, 2048*256)
  int row = i >> 8, c = (i & 255) * 4;
  float4 v = *(const float4*)&in[(size_t)row * 1536 + c];
  uint2 r = { pk(v.x, v.y), pk(v.z, v.w) };
  *(uint2*)&out[(size_t)row * 1024 + c] = r;
}

// ---------------------------------------------------------------------------
// C = A*W^T (+bias), A:[MxK] fp32 (lda), W:[NxK] fp32 (ldw), out bf16 [..xldo].
// tmaj: output row remap row -> (row&511)*64 + (row>>9)  (time-major (t,b)).
// 128x128 tile, 4 waves, 64x64/wave, 16x16x32 MFMA, cvt-to-bf16 in staging.
// ---------------------------------------------------------------------------
__global__ __launch_bounds__(256) void gemm_bt(
    const float* __restrict__ A, int lda,
    const float* __restrict__ W, int ldw,
    const float* __restrict__ bias1,
    ushort_t* __restrict__ out, int ldo, int K, int tmaj)
{
  __shared__ __align__(16) ushort_t sA[128][32];
  __shared__ __align__(16) ushort_t sW[128][32];
  const int tid = threadIdx.x;
  const int col0 = blockIdx.x * 128, row0 = blockIdx.y * 128;
  const int lane = tid & 63, wv = tid >> 6;
  const int wr = (wv & 1) * 64, wc = (wv >> 1) * 64;
  const int fr = lane & 15, quad = lane >> 4;
  const int sr = tid >> 1, skk = (tid & 1) * 16;
  f32x4 acc[4][4] = {};
  for (int k0 = 0; k0 < K; k0 += 32) {
    stage16(&sA[sr][skk], &A[(size_t)(row0 + sr) * lda + k0 + skk]);
    stage16(&sW[sr][skk], &W[(size_t)(col0 + sr) * ldw + k0 + skk]);
    __syncthreads();
    bf16x8 af[4], wf[4];
    #pragma unroll
    for (int mt = 0; mt < 4; ++mt) af[mt] = *(const bf16x8*)&sA[wr + mt*16 + fr][quad*8];
    #pragma unroll
    for (int nt = 0; nt < 4; ++nt) wf[nt] = *(const bf16x8*)&sW[wc + nt*16 + fr][quad*8];
    #pragma unroll
    for (int mt = 0; mt < 4; ++mt)
      #pragma unroll
      for (int nt = 0; nt < 4; ++nt)
        acc[mt][nt] = MFMA_BF16(af[mt], wf[nt], acc[mt][nt], 0, 0, 0);
    __syncthreads();
  }
  #pragma unroll
  for (int nt = 0; nt < 4; ++nt) {
    int col = col0 + wc + nt*16 + fr;
    float bs = bias1 ? bias1[col] : 0.f;
    #pragma unroll
    for (int mt = 0; mt < 4; ++mt)
      #pragma unroll
      for (int r = 0; r < 4; ++r) {
        int row = row0 + wr + mt*16 + quad*4 + r;
        int orow = tmaj ? ((row & 511) * 64 + (row >> 9)) : row;
        out[(size_t)orow * ldo + col] = f2bf(acc[mt][nt][r] + bs);
      }
  }
}

// ---------------------------------------------------------------------------
// Fence-free grid barrier: 8 group counters (128B apart) + root + generation.
// Sound because (a) __syncthreads drains vmcnt -> all coherent stores ack'd at
// MALL before lane 0 arrives; (b) every spin is bracketed by __syncthreads so
// the compiler cannot hoist post-barrier loads; (c) MALL is the single
// serialization point for all sc0sc1 traffic. 256 blocks, 1/CU -> co-resident.
// ---------------------------------------------------------------------------
__device__ __forceinline__ void grid_sync(unsigned* bar) {
  __syncthreads();
  if (threadIdx.x == 0) {
    unsigned* gen = bar + 288;
    unsigned g = __hip_atomic_load(gen, __ATOMIC_RELAXED, __HIP_MEMORY_SCOPE_AGENT);
    unsigned grp = blockIdx.x & 7u;
    unsigned old = __hip_atomic_fetch_add(bar + grp * 32, 1u,
                      __ATOMIC_RELAXED, __HIP_MEMORY_SCOPE_AGENT);
    if (old == 31u) {
      unsigned r = __hip_atomic_fetch_add(bar + 256, 1u,
                      __ATOMIC_RELAXED, __HIP_MEMORY_SCOPE_AGENT);
      if (r == 7u) {                       // last of all 256: reset, bump gen
        #pragma unroll
        for (int i = 0; i < 8; ++i)
          __hip_atomic_store(bar + i * 32, 0u, __ATOMIC_RELAXED, __HIP_MEMORY_SCOPE_AGENT);
        __hip_atomic_store(bar + 256, 0u, __ATOMIC_RELAXED, __HIP_MEMORY_SCOPE_AGENT);
        __builtin_amdgcn_s_waitcnt(0);     // resets globally ack'd before flip
        __hip_atomic_store(gen, g + 1u, __ATOMIC_RELAXED, __HIP_MEMORY_SCOPE_AGENT);
      } else {
        while (__hip_atomic_load(gen, __ATOMIC_RELAXED, __HIP_MEMORY_SCOPE_AGENT) == g)
          __builtin_amdgcn_s_sleep(4);
      }
    } else {
      while (__hip_atomic_load(gen, __ATOMIC_RELAXED, __HIP_MEMORY_SCOPE_AGENT) == g)
        __builtin_amdgcn_s_sleep(4);
    }
  }
  __syncthreads();
}

struct LoopArgs {
  const ushort_t *Sproj, *Vproj, *G, *Xproj;        // precomputed bf16 (Xproj may be null)
  const ushort_t *WRb, *Whhb, *Wihb;                // bf16 weights (Wihb: fallback only)
  const float *bR, *Ww, *bih, *bhh, *hv;            // fp32 inputs
  float *ru, *gpre, *beta;                          // cross-block scratch (coherent)
  uint_t *hbfd;                                     // recurrent h, bf16 packed as dwords
  unsigned *bar;
  float *out;                                       // (B,T,HI) fp32
};

// 256 blocks x 512 threads, persistent over T=512 steps, 3 barriers/step.
__global__ __launch_bounds__(512, 2) void loop_kernel(LoopArgs p) {
  const int blk = blockIdx.x, tid = threadIdx.x;
  const int lane = tid & 63, wv = tid >> 6;
  const int fr = lane & 15, quad = lane >> 4;
  const int b4 = blk >> 2, q4 = blk & 3;

  __shared__ __align__(16) float s_ru[512];
  __shared__ __align__(16) float s_ww[512];
  __shared__ __align__(16) float s_beta[5120];
  __shared__ float s_alpha[80];
  __shared__ float s_gates[512];
  __shared__ float s_h[128];

  s_ww[tid] = p.Ww[tid];
  float c_reg = 0.f;                                // cell state: register-resident

  for (int t = 0; t < 512; ++t) {
    // ====== P0: gates-hh MFMA (blk<64) + r_u MFMA (blk 64..79) =============
    if (blk < 64) {
      int w = blk * 8 + wv;                         // 0..511: nt x mt tiles
      int nt = w >> 2, mt = w & 3;
      int ncol = nt * 16 + fr;
      int mrow = mt * 16 + fr;                      // A row (batch) for this lane
      const uint_t* hrow = p.hbfd + mrow * 256;
      f32x4 acc = {};
      #pragma unroll
      for (int kc = 0; kc < 16; ++kc) {             // K=512 over h (coherent reads)
        int kd = kc * 16 + quad * 4;                // dword index
        uint4 av = { ldcg_u(hrow + kd),     ldcg_u(hrow + kd + 1),
                     ldcg_u(hrow + kd + 2), ldcg_u(hrow + kd + 3) };
        bf16x8 af = __builtin_bit_cast(bf16x8, av);
        bf16x8 wf = *(const bf16x8*)&p.Whhb[(size_t)ncol * 512 + kc * 32 + quad * 8];
        acc = MFMA_BF16(af, wf, acc, 0, 0, 0);
      }
      float bias = p.bih[ncol] + p.bhh[ncol];
      if (p.Xproj) {                                // hoisted X-projection
        #pragma unroll
        for (int r = 0; r < 4; ++r) {
          int b = mt * 16 + quad * 4 + r;
          float xv = bf2f(p.Xproj[(size_t)t * 131072 + b * 2048 + ncol]);
          stcg_f(&p.gpre[b * 2048 + ncol], acc[r] + xv + bias);
        }
      } else {                                      // in-loop X (fallback)
        f32x4 acc2 = {};
        #pragma unroll
        for (int kc = 0; kc < 32; ++kc) {
          int ko = kc * 32 + quad * 8;
          bf16x8 af = cvt8(&p.hv[((size_t)mrow * 512 + t) * 1024 + ko]);
          bf16x8 wf = *(const bf16x8*)&p.Wihb[(size_t)ncol * 1024 + ko];
          acc2 = MFMA_BF16(af, wf, acc2, 0, 0, 0);
        }
        #pragma unroll
        for (int r = 0; r < 4; ++r) {
          int b = mt * 16 + quad * 4 + r;
          stcg_f(&p.gpre[b * 2048 + ncol], acc[r] + acc2[r] + bias);
        }
      }
    } else if (blk < 80) {
      int w = (blk - 64) * 8 + wv;                  // 0..127
      int nt = w >> 2, mt = w & 3;
      int ncol = nt * 16 + fr;
      int mrow = mt * 16 + fr;
      const uint_t* hrow = p.hbfd + mrow * 256;
      f32x4 acc = {};
      #pragma unroll
      for (int kc = 0; kc < 16; ++kc) {
        int kd = kc * 16 + quad * 4;
        uint4 av = { ldcg_u(hrow + kd),     ldcg_u(hrow + kd + 1),
                     ldcg_u(hrow + kd + 2), ldcg_u(hrow + kd + 3) };
        bf16x8 af = __builtin_bit_cast(bf16x8, av);
        bf16x8 wf = *(const bf16x8*)&p.WRb[(size_t)ncol * 512 + kc * 32 + quad * 8];
        acc = MFMA_BF16(af, wf, acc, 0, 0, 0);
      }
      float br = p.bR[ncol];
      #pragma unroll
      for (int r = 0; r < 4; ++r) {
        int b = mt * 16 + quad * 4 + r;
        float vv = bf2f(p.Vproj[(size_t)t * 32768 + b * 512 + ncol]);
        stcg_f(&p.ru[b * 512 + ncol], acc[r] + br + vv);
      }
    }
    grid_sync(p.bar);

    // ====== P1: attention beta (all 256 blocks; (b4,q4) owns 20 n's) =======
    s_ru[tid] = ldcg_f(&p.ru[b4 * 512 + tid]);
    __syncthreads();
    #pragma unroll
    for (int rr = 0; rr < 3; ++rr) {
      int nl = wv + 8 * rr;
      if (nl < 20) {
        int n = q4 * 20 + nl;
        uint4 sv = *(const uint4*)&p.Sproj[((size_t)(b4 * 80 + n)) * 512 + lane * 8];
        float4 r0 = *(const float4*)&s_ru[lane * 8];
        float4 r1 = *(const float4*)&s_ru[lane * 8 + 4];
        float4 w0 = *(const float4*)&s_ww[lane * 8];
        float4 w1 = *(const float4*)&s_ww[lane * 8 + 4];
        float a = 0.f;
        a += tanh_(bf2f((ushort_t)(sv.x & 0xFFFF)) + r0.x) * w0.x;
        a += tanh_(bf2f((ushort_t)(sv.x >> 16))    + r0.y) * w0.y;
        a += tanh_(bf2f((ushort_t)(sv.y & 0xFFFF)) + r0.z) * w0.z;
        a += tanh_(bf2f((ushort_t)(sv.y >> 16))    + r0.w) * w0.w;
        a += tanh_(bf2f((ushort_t)(sv.z & 0xFFFF)) + r1.x) * w1.x;
        a += tanh_(bf2f((ushort_t)(sv.z >> 16))    + r1.y) * w1.y;
        a += tanh_(bf2f((ushort_t)(sv.w & 0xFFFF)) + r1.z) * w1.z;
        a += tanh_(bf2f((ushort_t)(sv.w >> 16))    + r1.w) * w1.w;
        #pragma unroll
        for (int off = 32; off > 0; off >>= 1) a += __shfl_xor(a, off, 64);
        if (lane == 0) stcg_f(&p.beta[b4 * 80 + n], a);
      }
    }
    grid_sync(p.bar);

    // ====== P2: batch-softmax + G-sum + LSTM pointwise =====================
    #pragma unroll
    for (int i = tid; i < 5120; i += 512) s_beta[i] = ldcg_f(&p.beta[i]);
    __syncthreads();
    if (tid < 80) {
      float m = -1e30f;
      for (int b2 = 0; b2 < 64; ++b2) m = fmaxf(m, s_beta[b2 * 80 + tid]);
      float s = 0.f;
      for (int b2 = 0; b2 < 64; ++b2) s += __expf(s_beta[b2 * 80 + tid] - m);
      s_alpha[tid] = __expf(s_beta[b4 * 80 + tid] - m) * __builtin_amdgcn_rcpf(s);
    }
    __syncthreads();
    {
      int gg = tid >> 7, jj = tid & 127;
      int k = gg * 512 + q4 * 128 + jj;
      const ushort_t* Gp = &p.G[(size_t)b4 * 80 * 2048 + k];
      float v0 = 0, v1 = 0, v2 = 0, v3 = 0;
      for (int n = 0; n < 80; n += 4) {
        v0 += s_alpha[n]     * bf2f(Gp[(size_t)n * 2048]);
        v1 += s_alpha[n + 1] * bf2f(Gp[(size_t)(n + 1) * 2048]);
        v2 += s_alpha[n + 2] * bf2f(Gp[(size_t)(n + 2) * 2048]);
        v3 += s_alpha[n + 3] * bf2f(Gp[(size_t)(n + 3) * 2048]);
      }
      s_gates[tid] = ldcg_f(&p.gpre[b4 * 2048 + k]) + ((v0 + v1) + (v2 + v3));
    }
    __syncthreads();
    if (tid < 128) {
      int j = q4 * 128 + tid;
      float ig = sigm_(s_gates[tid]);
      float fg = sigm_(s_gates[128 + tid]);
      float g_ = tanh_(s_gates[256 + tid]);
      float og = sigm_(s_gates[384 + tid]);
      float cn = fg * c_reg + ig * g_;
      c_reg = cn;
      float hn = og * tanh_(cn);
      s_h[tid] = hn;
      p.out[((size_t)b4 * 512 + t) * 512 + j] = hn;
    }
    __syncthreads();
    if (tid < 64)                                   // pack 2 x bf16, coherent store
      stcg_u(&p.hbfd[b4 * 256 + q4 * 64 + tid], pk(s_h[2 * tid], s_h[2 * tid + 1]));
    grid_sync(p.bar);
  }
}

// ===========================================================================
extern "C" void kernel_launch(void* const* d_in, const int* in_sizes, int n_in,
                              void* d_out, int out_size, void* d_ws, size_t ws_size,
                              hipStream_t stream) {
  (void)in_sizes; (void)n_in; (void)out_size;
  const float* hv   = (const float*)d_in[0];
  const float* hs   = (const float*)d_in[1];
  const float* W_S  = (const float*)d_in[2];
  const float* b_S  = (const float*)d_in[3];
  const float* W_V  = (const float*)d_in[4];
  const float* b_V  = (const float*)d_in[5];
  const float* W_R  = (const float*)d_in[6];
  const float* b_R  = (const float*)d_in[7];
  const float* W_w  = (const float*)d_in[8];
  /* d_in[9] = b_w: dropped */
  const float* W_ih = (const float*)d_in[10];
  const float* b_ih = (const float*)d_in[11];
  const float* W_hh = (const float*)d_in[12];
  const float* b_hh = (const float*)d_in[13];

  char* ws = (char*)d_ws;
  unsigned long long off = 0;
  auto alloc = [&](unsigned long long bytes) {
    unsigned long long pp = off; off += (bytes + 255ull) & ~255ull; return pp;
  };
  ushort_t* Sproj = (ushort_t*)(ws + alloc(5120ull * 512 * 2));
  ushort_t* Vproj = (ushort_t*)(ws + alloc(512ull * 64 * 512 * 2));   // time-major
  ushort_t* G     = (ushort_t*)(ws + alloc(5120ull * 2048 * 2));
  ushort_t* WRb   = (ushort_t*)(ws + alloc(512ull * 512 * 2));
  ushort_t* Whhb  = (ushort_t*)(ws + alloc(2048ull * 512 * 2));
  float*    ru    = (float*)(ws + alloc(64ull * 512 * 4));
  float*    gpre  = (float*)(ws + alloc(64ull * 2048 * 4));
  float*    beta  = (float*)(ws + alloc(64ull * 80 * 4));
  unsigned long long zoff = off;
  uint_t*   hbfd  = (uint_t*)(ws + alloc(64ull * 256 * 4));
  unsigned* bar   = (unsigned*)(ws + alloc(2048));
  unsigned long long zsize = off - zoff;
  unsigned long long tail = off;                    // Xproj or Wihb goes here
  bool precX = ws_size >= tail + 512ull * 64 * 2048 * 2 + 4096;
  ushort_t* Xproj = precX ? (ushort_t*)(ws + tail) : nullptr;
  ushort_t* Wihb  = precX ? nullptr : (ushort_t*)(ws + tail);

  cvt_kernel<<<256,  256, 0, stream>>>(W_R,  WRb,  512 * 512 / 4);
  cvt_kernel<<<1024, 256, 0, stream>>>(W_hh, Whhb, 2048 * 512 / 4);
  if (!precX) cvt_wih_kernel<<<2048, 256, 0, stream>>>(W_ih, Wihb);

  // S_proj = h_s.W_S^T + b_S            (5120 x 512, K=512), row-major
  gemm_bt<<<dim3(4, 40), 256, 0, stream>>>(hs, 512, W_S, 512, b_S, Sproj, 512, 512, 0);
  // V_proj = h_v.W_V^T + b_V            (32768 x 512, K=1024), time-major
  gemm_bt<<<dim3(4, 256), 256, 0, stream>>>(hv, 1024, W_V, 1024, b_V, Vproj, 512, 1024, 1);
  // G = h_s.(W_ih[:,1024:])^T           (5120 x 2048, K=512), row-major
  gemm_bt<<<dim3(16, 40), 256, 0, stream>>>(hs, 512, W_ih + 1024, 1536, nullptr, G, 2048, 512, 0);
  // Xproj = h_v.(W_ih[:, :1024])^T      (32768 x 2048, K=1024), time-major
  if (precX)
    gemm_bt<<<dim3(16, 256), 256, 0, stream>>>(hv, 1024, W_ih, 1536, nullptr, Xproj, 2048, 1024, 1);

  hipMemsetAsync(ws + zoff, 0, (size_t)zsize, stream);   // h=0, barrier=0

  LoopArgs la;
  la.Sproj = Sproj; la.Vproj = Vproj; la.G = G; la.Xproj = Xproj;
  la.WRb = WRb; la.Whhb = Whhb; la.Wihb = Wihb;
  la.bR = b_R; la.Ww = W_w; la.bih = b_ih; la.bhh = b_hh; la.hv = hv;
  la.ru = ru; la.gpre = gpre; la.beta = beta;
  la.hbfd = hbfd; la.bar = bar; la.out = (float*)d_out;
  loop_kernel<<<256, 512, 0, stream>>>(la);
}